// Round 7
// baseline (108.691 us; speedup 1.0000x reference)
//
#include <hip/hip_runtime.h>
#include <math.h>

#define Bb 4
#define Cc 32
#define Nn 200
#define Tt 2048
#define Ss 24
#define EPSf 1e-5f

typedef float f4 __attribute__((ext_vector_type(4)));
typedef int i4 __attribute__((ext_vector_type(4)));

// ws layout: float2 part[32][24][64]   (sum,sumsq per (c,slot,chunk))  384 KiB
//            int    cntpart[8][24]     (per (b,tt) histogram slice)    768 B
// Every slot is written unconditionally -> no zero-init kernel needed.

__global__ __launch_bounds__(256) void k_stats(const float* __restrict__ x,
                                               const int* __restrict__ timei,
                                               float2* __restrict__ part,
                                               int* __restrict__ cntpart) {
    __shared__ float lsum[Ss], lsq[Ss];
    __shared__ int   lcnt[Ss];
    const int tid = threadIdx.x;
    const int bx  = blockIdx.x;
    // grid = 2048: tt(2) x nc(8, 25-row chunks) x b(4) x c(32)
    const int tt = bx & 1;
    const int nc = (bx >> 1) & 7;
    const int bc = bx >> 4;
    const int b  = bc >> 5;
    const int c  = bc & 31;
    const bool do_hist = (c == 0 && nc == 0);

    if (tid < Ss) { lsum[tid] = 0.f; lsq[tid] = 0.f; lcnt[tid] = 0; }
    __syncthreads();

    const int t0 = tt * 1024 + tid * 4;
    const i4 sl = *(const i4*)(timei + b * Tt + t0);

    const size_t plane = ((size_t)(b * Cc + c) * Nn + (size_t)nc * 25) * Tt;
    const float* bp = x + plane + t0;

    float s0 = 0.f, s1 = 0.f, s2 = 0.f, s3 = 0.f;
    float q0 = 0.f, q1 = 0.f, q2 = 0.f, q3 = 0.f;
#pragma unroll 5
    for (int r = 0; r < 25; ++r) {
        f4 v = *(const f4*)(bp + (size_t)r * Tt);   // normal load: allocate in L3
        s0 += v[0]; q0 += v[0] * v[0];
        s1 += v[1]; q1 += v[1] * v[1];
        s2 += v[2]; q2 += v[2] * v[2];
        s3 += v[3]; q3 += v[3] * v[3];
    }

    atomicAdd(&lsum[sl[0]], s0); atomicAdd(&lsq[sl[0]], q0);
    atomicAdd(&lsum[sl[1]], s1); atomicAdd(&lsq[sl[1]], q1);
    atomicAdd(&lsum[sl[2]], s2); atomicAdd(&lsq[sl[2]], q2);
    atomicAdd(&lsum[sl[3]], s3); atomicAdd(&lsq[sl[3]], q3);
    if (do_hist) {
        atomicAdd(&lcnt[sl[0]], 1); atomicAdd(&lcnt[sl[1]], 1);
        atomicAdd(&lcnt[sl[2]], 1); atomicAdd(&lcnt[sl[3]], 1);
    }
    __syncthreads();

    const int chunk = (b * 2 + tt) * 8 + nc;   // [0,64)
    if (tid < Ss) {
        part[(c * Ss + tid) * 64 + chunk] = make_float2(lsum[tid], lsq[tid]);
        if (do_hist) cntpart[(b * 2 + tt) * Ss + tid] = lcnt[tid];
    }
}

__global__ __launch_bounds__(256) void k_norm(const float* __restrict__ x,
                                              const int* __restrict__ timei,
                                              const float2* __restrict__ part,
                                              const int* __restrict__ cntpart,
                                              float* __restrict__ out) {
    __shared__ float lsum[Ss], lsq[Ss];
    __shared__ float s_mr[Ss], s_r[Ss];
    const int tid = threadIdx.x;
    const int bx  = blockIdx.x;
    // grid = 512: b(4) x c(32) x nc(4, 50-row chunks)
    const int b  = bx >> 7;
    const int c  = (bx >> 2) & 31;
    const int nc = bx & 3;

    if (tid < Ss) { lsum[tid] = 0.f; lsq[tid] = 0.f; }
    __syncthreads();
    if (tid < 192) {                 // 24 slots x 8 groups of 8 chunks
        const int s = tid >> 3, j = tid & 7;
        const float2* pp = &part[(c * Ss + s) * 64 + j * 8];
        float ps = 0.f, pq = 0.f;
#pragma unroll
        for (int k = 0; k < 8; ++k) { ps += pp[k].x; pq += pp[k].y; }
        atomicAdd(&lsum[s], ps);
        atomicAdd(&lsq[s],  pq);
    }
    __syncthreads();
    if (tid < Ss) {
        int cnt = 0;
#pragma unroll
        for (int h = 0; h < 8; ++h) cnt += cntpart[h * Ss + tid];
        float denom = fmaxf((float)cnt, 1e-12f) * (float)Nn;
        float m  = lsum[tid] / denom;
        float m2 = lsq[tid]  / denom;
        float rr = 1.0f / sqrtf(m2 - m * m + EPSf);
        s_r[tid]  = rr;
        s_mr[tid] = m * rr;
    }
    __syncthreads();

    const int t0 = tid * 4;
    const i4 sl0 = *(const i4*)(timei + b * Tt + t0);
    const i4 sl1 = *(const i4*)(timei + b * Tt + t0 + 1024);
    const float rr0 = s_r[sl0[0]], mr0 = s_mr[sl0[0]];
    const float rr1 = s_r[sl0[1]], mr1 = s_mr[sl0[1]];
    const float rr2 = s_r[sl0[2]], mr2 = s_mr[sl0[2]];
    const float rr3 = s_r[sl0[3]], mr3 = s_mr[sl0[3]];
    const float rr4 = s_r[sl1[0]], mr4 = s_mr[sl1[0]];
    const float rr5 = s_r[sl1[1]], mr5 = s_mr[sl1[1]];
    const float rr6 = s_r[sl1[2]], mr6 = s_mr[sl1[2]];
    const float rr7 = s_r[sl1[3]], mr7 = s_mr[sl1[3]];

    const size_t plane = ((size_t)(b * Cc + c) * Nn + (size_t)nc * 50) * Tt;
    const float* xp = x + plane + t0;
    float* op = out + plane + t0;

#pragma unroll 5
    for (int r = 0; r < 50; ++r) {
        // nt load: still hits L3 (allocated by k_stats) but marks the line
        // evict-first afterward -> out-write allocations victimize consumed
        // x lines instead of unread ones.
        f4 v0 = __builtin_nontemporal_load((const f4*)(xp + (size_t)r * Tt));
        f4 v1 = __builtin_nontemporal_load((const f4*)(xp + (size_t)r * Tt + 1024));
        f4 o0, o1;
        o0[0] = fmaf(v0[0], rr0, -mr0);
        o0[1] = fmaf(v0[1], rr1, -mr1);
        o0[2] = fmaf(v0[2], rr2, -mr2);
        o0[3] = fmaf(v0[3], rr3, -mr3);
        o1[0] = fmaf(v1[0], rr4, -mr4);
        o1[1] = fmaf(v1[1], rr5, -mr5);
        o1[2] = fmaf(v1[2], rr6, -mr6);
        o1[3] = fmaf(v1[3], rr7, -mr7);
        __builtin_nontemporal_store(o0, (f4*)(op + (size_t)r * Tt));
        __builtin_nontemporal_store(o1, (f4*)(op + (size_t)r * Tt + 1024));
    }
}

extern "C" void kernel_launch(void* const* d_in, const int* in_sizes, int n_in,
                              void* d_out, int out_size, void* d_ws, size_t ws_size,
                              hipStream_t stream) {
    const float* x   = (const float*)d_in[0];
    const int* timei = (const int*)d_in[1];
    float* out = (float*)d_out;

    float2* part = (float2*)d_ws;                                  // 384 KiB
    int* cnt = (int*)((char*)d_ws + (size_t)Cc * Ss * 64 * sizeof(float2));

    k_stats<<<2048, 256, 0, stream>>>(x, timei, part, cnt);
    k_norm<<<512, 256, 0, stream>>>(x, timei, part, cnt, out);
}